// Round 6
// baseline (279.021 us; speedup 1.0000x reference)
//
#include <hip/hip_runtime.h>
#include <math.h>

// Problem constants (fixed by setup_inputs in the reference)
constexpr int B_ = 2, C_ = 64, H_ = 180, W_ = 360;
constexpr int HW = H_ * W_;             // 64800
constexpr int Hp = H_ + 2, Wp = W_ + 2; // padded dims 182 x 362
constexpr int CGROUPS = 4;              // channel groups (blocks) per pixel tile
constexpr int CPT = C_ / CGROUPS;       // channels per block = 16
constexpr int PXT = 256;                // pixels per block (4 waves/WG)
constexpr int TILES = (HW + PXT - 1) / PXT; // 254

// NOTE (round-5 lesson): the reference's seam mapping is DISCONTINUOUS in lon
// (remainder wraps + clamped 1-px-pad bicubic). Coordinate math must stay
// bit-close to fp32 libm: asinf/atan2f/exact-division remainder only.
__device__ __forceinline__ float frem(float x, float y) {
    // jnp.remainder for y > 0 (exact fp32 division, matches reference)
    return x - floorf(x / y) * y;
}

// bicubic weights, A = -0.75
__device__ __forceinline__ float cub1(float x) {   // |t| <= 1
    return (1.25f * x - 2.25f) * x * x + 1.0f;
}
__device__ __forceinline__ float cub2(float x) {   // 1 < |t| < 2
    return ((-0.75f * x + 3.75f) * x - 6.0f) * x + 3.0f;
}

// Read geo_cyclic_pad(hidden,1)[y][x] directly from the unpadded image.
// y in [0,Hp-1], x in [0,Wp-1]. Columns wrap; top/bottom rows are the first/
// last original row rolled by W/2 in longitude.
__device__ __forceinline__ float fetch_pad(const float* __restrict__ img, int y, int x) {
    int wc = x - 1;
    if (x == 0)      wc = W_ - 1;
    if (x == Wp - 1) wc = 0;
    int hh = y - 1;
    bool top = (y == 0), bot = (y == Hp - 1);
    if (top) hh = 0;
    if (bot) hh = H_ - 1;
    if (top || bot) { wc += W_ / 2; if (wc >= W_) wc -= W_; }
    return img[hh * W_ + wc];
}

__global__ __launch_bounds__(PXT, 6) void nsl_fused(
    const float* __restrict__ hidden,    // (B,C,H,W)
    const float* __restrict__ lat_grid,  // (B,H,W)
    const float* __restrict__ lon_grid,  // (B,H,W)
    const float* __restrict__ W_vel,     // (2C, C) row-major
    const float* __restrict__ b_vel,     // (2C)
    const float* __restrict__ dt_p,      // scalar
    float* __restrict__ out)             // (B,C,H,W)
{
    const int bid  = blockIdx.x;
    const int tile = bid % TILES;
    const int cg   = (bid / TILES) % CGROUPS;
    const int b    = bid / (TILES * CGROUPS);
    const int px   = tile * PXT + threadIdx.x;
    if (px >= HW) return;

    const float dt      = dt_p[0];
    const float min_lat = lat_grid[0];
    const float max_lat = lat_grid[(H_ - 1) * W_];   // lat monotone in h
    const float min_lon = lon_grid[0];
    const float max_lon = lon_grid[W_ - 1];          // lon monotone in w
    const float two_pi  = 6.28318530717958647f;

    const float lat_p = lat_grid[(size_t)b * HW + px];
    const float lon_p = lon_grid[(size_t)b * HW + px];
    float sp, cp;
    __sincosf(lat_p, &sp, &cp);

    // ---- Phase 1: k-streaming 1x1-conv GEMM ----
    // CPT (u,v) accumulator pairs stay in VGPRs; each input channel k is
    // loaded ONCE (coalesced) and applied to all CPT outputs with
    // block-uniform W_vel operands (scalar pipe).
    float u[CPT], v[CPT];
#pragma unroll
    for (int i = 0; i < CPT; ++i) {
        u[i] = b_vel[cg * CPT + i];
        v[i] = b_vel[C_ + cg * CPT + i];
    }
    const float* hb = hidden + (size_t)b * C_ * HW + px;
#pragma unroll 2
    for (int k = 0; k < C_; ++k) {
        const float x = hb[(size_t)k * HW];
#pragma unroll
        for (int i = 0; i < CPT; ++i) {
            u[i] = fmaf(W_vel[(size_t)(cg * CPT + i) * C_ + k], x, u[i]);
            v[i] = fmaf(W_vel[(size_t)(C_ + cg * CPT + i) * C_ + k], x, v[i]);
        }
    }

    const float inv_dlat = 2.0f / (max_lat - min_lat);
    const float inv_dlon = 2.0f / (max_lon - min_lon);
    const float sxw = (float)W_ / (float)Wp;
    const float syh = (float)H_ / (float)Hp;

    // ---- Phase 2: per-channel departure point + bicubic gather ----
    for (int i = 0; i < CPT; ++i) {
        const int c = cg * CPT + i;                 // block-uniform channel

        // departure point on the sphere (exact libm — see seam note above)
        const float lon_pr = -u[i] * dt;
        const float lat_pr = -v[i] * dt;
        float slp, clp, slo, clo;
        __sincosf(lat_pr, &slp, &clp);
        __sincosf(lon_pr, &slo, &clo);
        float sin_lat = slp * cp + clp * clo * sp;
        sin_lat = fminf(fmaxf(sin_lat, -1.0f + 1e-7f), 1.0f - 1e-7f);
        const float lat = asinf(sin_lat);
        const float num = clp * slo;
        const float den = clp * clo * cp - slp * sp;
        const float lon = frem(lon_p + atan2f(num, den) + two_pi, two_pi);

        // normalized grid coords with cyclic/pole wrapping
        float gx = (lon - min_lon) * inv_dlon - 1.0f;
        float gy = (lat - min_lat) * inv_dlat - 1.0f;
        gx = frem(gx + 1.0f, 2.0f) - 1.0f;
        const bool left  = (gx <= 0.0f);
        const bool outer = (fabsf(gy) > 1.0f);
        if (outer) gx += left ? 1.0f : -1.0f;
        if (gy < -1.0f)     gy = -(2.0f + gy);
        else if (gy > 1.0f) gy = 2.0f - gy;
        gx *= sxw;
        gy *= syh;

        // bicubic sample of the (virtually) padded image
        const float ix = (gx + 1.0f) * 0.5f * (float)(Wp - 1);
        const float iy = (gy + 1.0f) * 0.5f * (float)(Hp - 1);
        const float fx0 = floorf(ix), fy0 = floorf(iy);
        const float tx = ix - fx0, ty = iy - fy0;
        const int jx = (int)fx0, jy = (int)fy0;

        const float* __restrict__ img = hidden + ((size_t)b * C_ + c) * HW;

        // taps: padded coords (jy-1+r, jx-1+cc), r,cc in 0..3
        float t[16];
        const bool interior = (jx >= 2) & (jx <= Wp - 4) & (jy >= 2) & (jy <= Hp - 4);
        if (__all(interior)) {
            // all lanes' 4x4 footprints avoid pad rows/cols and clamps:
            // padded (jy-1+r, jx-1+cc) -> unpadded (jy-2+r, jx-2+cc)
            const float* __restrict__ p = img + (jy - 2) * W_ + (jx - 2);
#pragma unroll
            for (int r = 0; r < 4; ++r)
#pragma unroll
                for (int cc = 0; cc < 4; ++cc)
                    t[r * 4 + cc] = p[r * W_ + cc];   // base + imm offsets
        } else {
            int xs[4], ys[4];
#pragma unroll
            for (int r = 0; r < 4; ++r) {
                xs[r] = min(max(jx - 1 + r, 0), Wp - 1);
                ys[r] = min(max(jy - 1 + r, 0), Hp - 1);
            }
#pragma unroll
            for (int r = 0; r < 4; ++r)
#pragma unroll
                for (int cc = 0; cc < 4; ++cc)
                    t[r * 4 + cc] = fetch_pad(img, ys[r], xs[cc]);
        }

        const float wx0 = cub2(tx + 1.0f), wx1 = cub1(tx);
        const float wx2 = cub1(1.0f - tx), wx3 = cub2(2.0f - tx);
        const float wy0 = cub2(ty + 1.0f), wy1 = cub1(ty);
        const float wy2 = cub1(1.0f - ty), wy3 = cub2(2.0f - ty);

        const float r0 = fmaf(wx3, t[3],  fmaf(wx2, t[2],  fmaf(wx1, t[1],  wx0 * t[0])));
        const float r1 = fmaf(wx3, t[7],  fmaf(wx2, t[6],  fmaf(wx1, t[5],  wx0 * t[4])));
        const float r2 = fmaf(wx3, t[11], fmaf(wx2, t[10], fmaf(wx1, t[9],  wx0 * t[8])));
        const float r3 = fmaf(wx3, t[15], fmaf(wx2, t[14], fmaf(wx1, t[13], wx0 * t[12])));

        out[((size_t)b * C_ + c) * HW + px] =
            fmaf(wy3, r3, fmaf(wy2, r2, fmaf(wy1, r1, wy0 * r0)));
    }
}

extern "C" void kernel_launch(void* const* d_in, const int* in_sizes, int n_in,
                              void* d_out, int out_size, void* d_ws, size_t ws_size,
                              hipStream_t stream) {
    const float* hidden   = (const float*)d_in[0];
    const float* lat_grid = (const float*)d_in[1];
    const float* lon_grid = (const float*)d_in[2];
    const float* W_vel    = (const float*)d_in[3];
    const float* b_vel    = (const float*)d_in[4];
    const float* dt_p     = (const float*)d_in[5];
    float* out = (float*)d_out;

    const int grid = B_ * CGROUPS * TILES; // 2032 blocks of 4 waves
    nsl_fused<<<grid, PXT, 0, stream>>>(hidden, lat_grid, lon_grid, W_vel, b_vel, dt_p, out);
}

// Round 7
// 243.050 us; speedup vs baseline: 1.1480x; 1.1480x over previous
//
#include <hip/hip_runtime.h>
#include <math.h>

// Problem constants (fixed by setup_inputs in the reference)
constexpr int B_ = 2, C_ = 64, H_ = 180, W_ = 360;
constexpr int HW = H_ * W_;             // 64800
constexpr int Hp = H_ + 2, Wp = W_ + 2; // padded dims 182 x 362
constexpr int O_ = 2 * C_;              // 128 velocity outputs

// NOTE (round-5 lesson): the reference's seam mapping is DISCONTINUOUS in lon
// (remainder wraps + clamped 1-px-pad bicubic). Coordinate math must stay
// bit-close to fp32 libm: asinf/atan2f/exact-division remainder only.
__device__ __forceinline__ float frem(float x, float y) {
    return x - floorf(x / y) * y;
}

// bicubic weights, A = -0.75
__device__ __forceinline__ float cub1(float x) {   // |t| <= 1
    return (1.25f * x - 2.25f) * x * x + 1.0f;
}
__device__ __forceinline__ float cub2(float x) {   // 1 < |t| < 2
    return ((-0.75f * x + 3.75f) * x - 6.0f) * x + 3.0f;
}

// Read geo_cyclic_pad(hidden,1)[y][x] directly from the unpadded image.
__device__ __forceinline__ float fetch_pad(const float* __restrict__ img, int y, int x) {
    int wc = x - 1;
    if (x == 0)      wc = W_ - 1;
    if (x == Wp - 1) wc = 0;
    int hh = y - 1;
    bool top = (y == 0), bot = (y == Hp - 1);
    if (top) hh = 0;
    if (bot) hh = H_ - 1;
    if (top || bot) { wc += W_ / 2; if (wc >= W_) wc -= W_; }
    return img[hh * W_ + wc];
}

// Shared phase-2 math: departure point + bicubic sample for one (b,c,px).
__device__ __forceinline__ float advect_one(
    const float* __restrict__ img,   // channel slice (H,W)
    float u, float v, float dt,
    float sp, float cp, float lon_p,
    float min_lat, float min_lon, float inv_dlat, float inv_dlon)
{
    const float two_pi = 6.28318530717958647f;
    const float sxw = (float)W_ / (float)Wp;
    const float syh = (float)H_ / (float)Hp;

    const float lon_pr = -u * dt;
    const float lat_pr = -v * dt;
    float slp, clp, slo, clo;
    __sincosf(lat_pr, &slp, &clp);
    __sincosf(lon_pr, &slo, &clo);
    float sin_lat = slp * cp + clp * clo * sp;
    sin_lat = fminf(fmaxf(sin_lat, -1.0f + 1e-7f), 1.0f - 1e-7f);
    const float lat = asinf(sin_lat);
    const float num = clp * slo;
    const float den = clp * clo * cp - slp * sp;
    const float lon = frem(lon_p + atan2f(num, den) + two_pi, two_pi);

    float gx = (lon - min_lon) * inv_dlon - 1.0f;
    float gy = (lat - min_lat) * inv_dlat - 1.0f;
    gx = frem(gx + 1.0f, 2.0f) - 1.0f;
    const bool left  = (gx <= 0.0f);
    const bool outer = (fabsf(gy) > 1.0f);
    if (outer) gx += left ? 1.0f : -1.0f;
    if (gy < -1.0f)     gy = -(2.0f + gy);
    else if (gy > 1.0f) gy = 2.0f - gy;
    gx *= sxw;
    gy *= syh;

    const float ix = (gx + 1.0f) * 0.5f * (float)(Wp - 1);
    const float iy = (gy + 1.0f) * 0.5f * (float)(Hp - 1);
    const float fx0 = floorf(ix), fy0 = floorf(iy);
    const float tx = ix - fx0, ty = iy - fy0;
    const int jx = (int)fx0, jy = (int)fy0;

    float t[16];
    const bool interior = (jx >= 2) & (jx <= Wp - 4) & (jy >= 2) & (jy <= Hp - 4);
    if (__all(interior)) {
        const float* __restrict__ p = img + (jy - 2) * W_ + (jx - 2);
#pragma unroll
        for (int r = 0; r < 4; ++r)
#pragma unroll
            for (int cc = 0; cc < 4; ++cc)
                t[r * 4 + cc] = p[r * W_ + cc];
    } else {
        int xs[4], ys[4];
#pragma unroll
        for (int r = 0; r < 4; ++r) {
            xs[r] = min(max(jx - 1 + r, 0), Wp - 1);
            ys[r] = min(max(jy - 1 + r, 0), Hp - 1);
        }
#pragma unroll
        for (int r = 0; r < 4; ++r)
#pragma unroll
            for (int cc = 0; cc < 4; ++cc)
                t[r * 4 + cc] = fetch_pad(img, ys[r], xs[cc]);
    }

    const float wx0 = cub2(tx + 1.0f), wx1 = cub1(tx);
    const float wx2 = cub1(1.0f - tx), wx3 = cub2(2.0f - tx);
    const float wy0 = cub2(ty + 1.0f), wy1 = cub1(ty);
    const float wy2 = cub1(1.0f - ty), wy3 = cub2(2.0f - ty);

    const float r0 = fmaf(wx3, t[3],  fmaf(wx2, t[2],  fmaf(wx1, t[1],  wx0 * t[0])));
    const float r1 = fmaf(wx3, t[7],  fmaf(wx2, t[6],  fmaf(wx1, t[5],  wx0 * t[4])));
    const float r2 = fmaf(wx3, t[11], fmaf(wx2, t[10], fmaf(wx1, t[9],  wx0 * t[8])));
    const float r3 = fmaf(wx3, t[15], fmaf(wx2, t[14], fmaf(wx1, t[13], wx0 * t[12])));

    return fmaf(wy3, r3, fmaf(wy2, r2, fmaf(wy1, r1, wy0 * r0)));
}

// ---------------- Phase 1: uv = hidden x W_vel^T + b (B,128,HW) ----------------
constexpr int P1_PXT = 256;
constexpr int P1_OG  = 4;               // output groups
constexpr int P1_OPG = O_ / P1_OG;      // 32 outputs per group
constexpr int P1_TILES = (HW + P1_PXT - 1) / P1_PXT; // 254

__global__ __launch_bounds__(P1_PXT, 6) void nsl_vel(
    const float* __restrict__ hidden, const float* __restrict__ W_vel,
    const float* __restrict__ b_vel, float* __restrict__ uv)
{
    const int bid  = blockIdx.x;
    const int tile = bid % P1_TILES;
    const int og   = (bid / P1_TILES) % P1_OG;
    const int b    = bid / (P1_TILES * P1_OG);
    const int px   = tile * P1_PXT + threadIdx.x;
    if (px >= HW) return;

    float acc[P1_OPG];
#pragma unroll
    for (int j = 0; j < P1_OPG; ++j) acc[j] = b_vel[og * P1_OPG + j];

    const float* hb = hidden + (size_t)b * C_ * HW + px;
#pragma unroll 2
    for (int k = 0; k < C_; ++k) {
        const float x = hb[(size_t)k * HW];
#pragma unroll
        for (int j = 0; j < P1_OPG; ++j)
            acc[j] = fmaf(W_vel[(size_t)(og * P1_OPG + j) * C_ + k], x, acc[j]);
    }

    float* o = uv + ((size_t)b * O_ + og * P1_OPG) * HW + px;
#pragma unroll
    for (int j = 0; j < P1_OPG; ++j) o[(size_t)j * HW] = acc[j];
}

// ---------------- Phase 2: one thread per (b,c,px) ----------------
__global__ __launch_bounds__(256, 6) void nsl_advect(
    const float* __restrict__ hidden,    // (B,C,H,W)
    const float* __restrict__ lat_grid,  // (B,H,W)
    const float* __restrict__ lon_grid,  // (B,H,W)
    const float* __restrict__ uv,        // (B,128,HW) from phase 1
    const float* __restrict__ dt_p,
    float* __restrict__ out)             // (B,C,H,W)
{
    const int idx = blockIdx.x * 256 + threadIdx.x;
    if (idx >= B_ * C_ * HW) return;
    const int px = idx % HW;
    const int bc = idx / HW;            // b*C + c
    const int b  = bc / C_;
    const int c  = bc - b * C_;

    const float dt      = dt_p[0];
    const float min_lat = lat_grid[0];
    const float max_lat = lat_grid[(H_ - 1) * W_];
    const float min_lon = lon_grid[0];
    const float max_lon = lon_grid[W_ - 1];
    const float inv_dlat = 2.0f / (max_lat - min_lat);
    const float inv_dlon = 2.0f / (max_lon - min_lon);

    const float lat_p = lat_grid[(size_t)b * HW + px];
    const float lon_p = lon_grid[(size_t)b * HW + px];
    float sp, cp;
    __sincosf(lat_p, &sp, &cp);

    const float u = uv[((size_t)b * O_ + c) * HW + px];
    const float v = uv[((size_t)b * O_ + C_ + c) * HW + px];

    const float* __restrict__ img = hidden + (size_t)bc * HW;
    out[(size_t)bc * HW + px] = advect_one(img, u, v, dt, sp, cp, lon_p,
                                           min_lat, min_lon, inv_dlat, inv_dlon);
}

// ---------------- Fallback: round-6 fused kernel (passing) ----------------
constexpr int FB_CG = 4, FB_CPT = C_ / FB_CG, FB_PXT = 256;
constexpr int FB_TILES = (HW + FB_PXT - 1) / FB_PXT;

__global__ __launch_bounds__(FB_PXT, 6) void nsl_fused(
    const float* __restrict__ hidden, const float* __restrict__ lat_grid,
    const float* __restrict__ lon_grid, const float* __restrict__ W_vel,
    const float* __restrict__ b_vel, const float* __restrict__ dt_p,
    float* __restrict__ out)
{
    const int bid  = blockIdx.x;
    const int tile = bid % FB_TILES;
    const int cg   = (bid / FB_TILES) % FB_CG;
    const int b    = bid / (FB_TILES * FB_CG);
    const int px   = tile * FB_PXT + threadIdx.x;
    if (px >= HW) return;

    const float dt      = dt_p[0];
    const float min_lat = lat_grid[0];
    const float max_lat = lat_grid[(H_ - 1) * W_];
    const float min_lon = lon_grid[0];
    const float max_lon = lon_grid[W_ - 1];
    const float inv_dlat = 2.0f / (max_lat - min_lat);
    const float inv_dlon = 2.0f / (max_lon - min_lon);

    const float lat_p = lat_grid[(size_t)b * HW + px];
    const float lon_p = lon_grid[(size_t)b * HW + px];
    float sp, cp;
    __sincosf(lat_p, &sp, &cp);

    float u[FB_CPT], v[FB_CPT];
#pragma unroll
    for (int i = 0; i < FB_CPT; ++i) {
        u[i] = b_vel[cg * FB_CPT + i];
        v[i] = b_vel[C_ + cg * FB_CPT + i];
    }
    const float* hb = hidden + (size_t)b * C_ * HW + px;
#pragma unroll 2
    for (int k = 0; k < C_; ++k) {
        const float x = hb[(size_t)k * HW];
#pragma unroll
        for (int i = 0; i < FB_CPT; ++i) {
            u[i] = fmaf(W_vel[(size_t)(cg * FB_CPT + i) * C_ + k], x, u[i]);
            v[i] = fmaf(W_vel[(size_t)(C_ + cg * FB_CPT + i) * C_ + k], x, v[i]);
        }
    }

    for (int i = 0; i < FB_CPT; ++i) {
        const int c = cg * FB_CPT + i;
        const float* __restrict__ img = hidden + ((size_t)b * C_ + c) * HW;
        out[((size_t)b * C_ + c) * HW + px] =
            advect_one(img, u[i], v[i], dt, sp, cp, lon_p,
                       min_lat, min_lon, inv_dlat, inv_dlon);
    }
}

extern "C" void kernel_launch(void* const* d_in, const int* in_sizes, int n_in,
                              void* d_out, int out_size, void* d_ws, size_t ws_size,
                              hipStream_t stream) {
    const float* hidden   = (const float*)d_in[0];
    const float* lat_grid = (const float*)d_in[1];
    const float* lon_grid = (const float*)d_in[2];
    const float* W_vel    = (const float*)d_in[3];
    const float* b_vel    = (const float*)d_in[4];
    const float* dt_p     = (const float*)d_in[5];
    float* out = (float*)d_out;

    const size_t uv_bytes = (size_t)B_ * O_ * HW * sizeof(float); // 66.4 MB
    if (ws_size >= uv_bytes) {
        float* uv = (float*)d_ws;
        nsl_vel<<<B_ * P1_OG * P1_TILES, P1_PXT, 0, stream>>>(hidden, W_vel, b_vel, uv);
        const int n2 = B_ * C_ * HW;
        nsl_advect<<<(n2 + 255) / 256, 256, 0, stream>>>(hidden, lat_grid, lon_grid,
                                                         uv, dt_p, out);
    } else {
        nsl_fused<<<B_ * FB_CG * FB_TILES, FB_PXT, 0, stream>>>(
            hidden, lat_grid, lon_grid, W_vel, b_vel, dt_p, out);
    }
}

// Round 8
// 239.439 us; speedup vs baseline: 1.1653x; 1.0151x over previous
//
#include <hip/hip_runtime.h>
#include <math.h>

// Problem constants (fixed by setup_inputs in the reference)
constexpr int B_ = 2, C_ = 64, H_ = 180, W_ = 360;
constexpr int HW = H_ * W_;             // 64800
constexpr int Hp = H_ + 2, Wp = W_ + 2; // padded dims 182 x 362
constexpr int O_ = 2 * C_;              // 128 velocity outputs

// NOTE (round-5 lesson): the reference's seam mapping is DISCONTINUOUS in lon
// (remainder wraps + clamped 1-px-pad bicubic). Coordinate math must stay
// bit-close to fp32 libm: asinf/atan2f/exact-division remainder only.
__device__ __forceinline__ float frem(float x, float y) {
    return x - floorf(x / y) * y;            // IEEE division, matches jnp
}
// remainder(x, 2): x*0.5f is EXACT (pow2), floor identical to floor(x/2).
__device__ __forceinline__ float frem2(float x) {
    return x - floorf(x * 0.5f) * 2.0f;
}

// bicubic weights, A = -0.75
__device__ __forceinline__ float cub1(float x) {   // |t| <= 1
    return (1.25f * x - 2.25f) * x * x + 1.0f;
}
__device__ __forceinline__ float cub2(float x) {   // 1 < |t| < 2
    return ((-0.75f * x + 3.75f) * x - 6.0f) * x + 3.0f;
}

// Read geo_cyclic_pad(hidden,1)[y][x] directly from the unpadded image.
__device__ __forceinline__ float fetch_pad(const float* __restrict__ img, int y, int x) {
    int wc = x - 1;
    if (x == 0)      wc = W_ - 1;
    if (x == Wp - 1) wc = 0;
    int hh = y - 1;
    bool top = (y == 0), bot = (y == Hp - 1);
    if (top) hh = 0;
    if (bot) hh = H_ - 1;
    if (top || bot) { wc += W_ / 2; if (wc >= W_) wc -= W_; }
    return img[hh * W_ + wc];
}

// Shared phase-2 math: departure point + bicubic sample for one (b,c,px).
__device__ __forceinline__ float advect_one(
    const float* __restrict__ img,   // channel slice (H,W)
    float u, float v, float dt,
    float sp, float cp, float lon_p,
    float min_lat, float min_lon, float inv_dlat, float inv_dlon)
{
    const float two_pi = 6.28318530717958647f;
    const float sxw = (float)W_ / (float)Wp;
    const float syh = (float)H_ / (float)Hp;

    const float lon_pr = -u * dt;
    const float lat_pr = -v * dt;
    float slp, clp, slo, clo;
    __sincosf(lat_pr, &slp, &clp);
    __sincosf(lon_pr, &slo, &clo);
    float sin_lat = slp * cp + clp * clo * sp;
    sin_lat = fminf(fmaxf(sin_lat, -1.0f + 1e-7f), 1.0f - 1e-7f);
    const float lat = asinf(sin_lat);
    const float num = clp * slo;
    const float den = clp * clo * cp - slp * sp;
    const float lon = frem(lon_p + atan2f(num, den) + two_pi, two_pi);

    float gx = (lon - min_lon) * inv_dlon - 1.0f;
    float gy = (lat - min_lat) * inv_dlat - 1.0f;
    gx = frem2(gx + 1.0f) - 1.0f;
    const bool left  = (gx <= 0.0f);
    const bool outer = (fabsf(gy) > 1.0f);
    if (outer) gx += left ? 1.0f : -1.0f;
    if (gy < -1.0f)     gy = -(2.0f + gy);
    else if (gy > 1.0f) gy = 2.0f - gy;
    gx *= sxw;
    gy *= syh;

    const float ix = (gx + 1.0f) * 0.5f * (float)(Wp - 1);
    const float iy = (gy + 1.0f) * 0.5f * (float)(Hp - 1);
    const float fx0 = floorf(ix), fy0 = floorf(iy);
    const float tx = ix - fx0, ty = iy - fy0;
    const int jx = (int)fx0, jy = (int)fy0;

    float t[16];
    const bool interior = (jx >= 2) & (jx <= Wp - 4) & (jy >= 2) & (jy <= Hp - 4);
    if (__all(interior)) {
        const float* __restrict__ p = img + (jy - 2) * W_ + (jx - 2);
#pragma unroll
        for (int r = 0; r < 4; ++r)
#pragma unroll
            for (int cc = 0; cc < 4; ++cc)
                t[r * 4 + cc] = p[r * W_ + cc];
    } else {
        int xs[4], ys[4];
#pragma unroll
        for (int r = 0; r < 4; ++r) {
            xs[r] = min(max(jx - 1 + r, 0), Wp - 1);
            ys[r] = min(max(jy - 1 + r, 0), Hp - 1);
        }
#pragma unroll
        for (int r = 0; r < 4; ++r)
#pragma unroll
            for (int cc = 0; cc < 4; ++cc)
                t[r * 4 + cc] = fetch_pad(img, ys[r], xs[cc]);
    }

    const float wx0 = cub2(tx + 1.0f), wx1 = cub1(tx);
    const float wx2 = cub1(1.0f - tx), wx3 = cub2(2.0f - tx);
    const float wy0 = cub2(ty + 1.0f), wy1 = cub1(ty);
    const float wy2 = cub1(1.0f - ty), wy3 = cub2(2.0f - ty);

    const float r0 = fmaf(wx3, t[3],  fmaf(wx2, t[2],  fmaf(wx1, t[1],  wx0 * t[0])));
    const float r1 = fmaf(wx3, t[7],  fmaf(wx2, t[6],  fmaf(wx1, t[5],  wx0 * t[4])));
    const float r2 = fmaf(wx3, t[11], fmaf(wx2, t[10], fmaf(wx1, t[9],  wx0 * t[8])));
    const float r3 = fmaf(wx3, t[15], fmaf(wx2, t[14], fmaf(wx1, t[13], wx0 * t[12])));

    return fmaf(wy3, r3, fmaf(wy2, r2, fmaf(wy1, r1, wy0 * r0)));
}

// ---------------- Phase 1: uv = hidden x W_vel^T + b  (B,128,HW) ----------------
// OG=2: each block computes 64 outputs for 256 pixels; hidden read only 2x.
// 4-deep explicit prefetch; 64 FMAs per loaded element cover load latency.
constexpr int P1_PXT = 256;
constexpr int P1_OG  = 2;
constexpr int P1_OPG = O_ / P1_OG;      // 64 outputs per group
constexpr int P1_TILES = (HW + P1_PXT - 1) / P1_PXT; // 254

__global__ __launch_bounds__(P1_PXT, 4) void nsl_vel(
    const float* __restrict__ hidden, const float* __restrict__ W_vel,
    const float* __restrict__ b_vel, float* __restrict__ uv)
{
    const int bid  = blockIdx.x;
    const int tile = bid % P1_TILES;
    const int og   = (bid / P1_TILES) % P1_OG;
    const int b    = bid / (P1_TILES * P1_OG);
    const int px   = tile * P1_PXT + threadIdx.x;
    if (px >= HW) return;

    float acc[P1_OPG];
#pragma unroll
    for (int j = 0; j < P1_OPG; ++j) acc[j] = b_vel[og * P1_OPG + j];

    const float* hb = hidden + (size_t)b * C_ * HW + px;
    const float* Wg = W_vel + (size_t)og * P1_OPG * C_;

    float xf[4];
#pragma unroll
    for (int t = 0; t < 4; ++t) xf[t] = hb[(size_t)t * HW];

    for (int k0 = 0; k0 < C_; k0 += 4) {
        float xc[4];
#pragma unroll
        for (int t = 0; t < 4; ++t) xc[t] = xf[t];
        if (k0 + 4 < C_) {
#pragma unroll
            for (int t = 0; t < 4; ++t) xf[t] = hb[(size_t)(k0 + 4 + t) * HW];
        }
        // k-chain per output stays ascending -> bitwise-identical uv.
        // W reads: 4 contiguous floats per j (s_load_dwordx4-friendly).
#pragma unroll
        for (int j = 0; j < P1_OPG; ++j) {
            const float* wr = Wg + (size_t)j * C_ + k0;
            acc[j] = fmaf(wr[0], xc[0], acc[j]);
            acc[j] = fmaf(wr[1], xc[1], acc[j]);
            acc[j] = fmaf(wr[2], xc[2], acc[j]);
            acc[j] = fmaf(wr[3], xc[3], acc[j]);
        }
    }

    float* o = uv + ((size_t)b * O_ + og * P1_OPG) * HW + px;
#pragma unroll
    for (int j = 0; j < P1_OPG; ++j) o[(size_t)j * HW] = acc[j];
}

// ---------------- Phase 2: one thread per (b,c,px) ----------------
__global__ __launch_bounds__(256, 6) void nsl_advect(
    const float* __restrict__ hidden,    // (B,C,H,W)
    const float* __restrict__ lat_grid,  // (B,H,W)
    const float* __restrict__ lon_grid,  // (B,H,W)
    const float* __restrict__ uv,        // (B,128,HW) from phase 1
    const float* __restrict__ dt_p,
    float* __restrict__ out)             // (B,C,H,W)
{
    const int idx = blockIdx.x * 256 + threadIdx.x;
    if (idx >= B_ * C_ * HW) return;
    const int px = idx % HW;
    const int bc = idx / HW;            // b*C + c
    const int b  = bc / C_;
    const int c  = bc - b * C_;

    const float dt      = dt_p[0];
    const float min_lat = lat_grid[0];
    const float max_lat = lat_grid[(H_ - 1) * W_];
    const float min_lon = lon_grid[0];
    const float max_lon = lon_grid[W_ - 1];
    const float inv_dlat = 2.0f / (max_lat - min_lat);
    const float inv_dlon = 2.0f / (max_lon - min_lon);

    const float lat_p = lat_grid[(size_t)b * HW + px];
    const float lon_p = lon_grid[(size_t)b * HW + px];
    float sp, cp;
    __sincosf(lat_p, &sp, &cp);

    const float u = uv[((size_t)b * O_ + c) * HW + px];
    const float v = uv[((size_t)b * O_ + C_ + c) * HW + px];

    const float* __restrict__ img = hidden + (size_t)bc * HW;
    out[(size_t)bc * HW + px] = advect_one(img, u, v, dt, sp, cp, lon_p,
                                           min_lat, min_lon, inv_dlat, inv_dlon);
}

// ---------------- Fallback: fused kernel (round-6 structure, passing) ----------------
constexpr int FB_CG = 4, FB_CPT = C_ / FB_CG, FB_PXT = 256;
constexpr int FB_TILES = (HW + FB_PXT - 1) / FB_PXT;

__global__ __launch_bounds__(FB_PXT, 6) void nsl_fused(
    const float* __restrict__ hidden, const float* __restrict__ lat_grid,
    const float* __restrict__ lon_grid, const float* __restrict__ W_vel,
    const float* __restrict__ b_vel, const float* __restrict__ dt_p,
    float* __restrict__ out)
{
    const int bid  = blockIdx.x;
    const int tile = bid % FB_TILES;
    const int cg   = (bid / FB_TILES) % FB_CG;
    const int b    = bid / (FB_TILES * FB_CG);
    const int px   = tile * FB_PXT + threadIdx.x;
    if (px >= HW) return;

    const float dt      = dt_p[0];
    const float min_lat = lat_grid[0];
    const float max_lat = lat_grid[(H_ - 1) * W_];
    const float min_lon = lon_grid[0];
    const float max_lon = lon_grid[W_ - 1];
    const float inv_dlat = 2.0f / (max_lat - min_lat);
    const float inv_dlon = 2.0f / (max_lon - min_lon);

    const float lat_p = lat_grid[(size_t)b * HW + px];
    const float lon_p = lon_grid[(size_t)b * HW + px];
    float sp, cp;
    __sincosf(lat_p, &sp, &cp);

    float u[FB_CPT], v[FB_CPT];
#pragma unroll
    for (int i = 0; i < FB_CPT; ++i) {
        u[i] = b_vel[cg * FB_CPT + i];
        v[i] = b_vel[C_ + cg * FB_CPT + i];
    }
    const float* hb = hidden + (size_t)b * C_ * HW + px;
#pragma unroll 2
    for (int k = 0; k < C_; ++k) {
        const float x = hb[(size_t)k * HW];
#pragma unroll
        for (int i = 0; i < FB_CPT; ++i) {
            u[i] = fmaf(W_vel[(size_t)(cg * FB_CPT + i) * C_ + k], x, u[i]);
            v[i] = fmaf(W_vel[(size_t)(C_ + cg * FB_CPT + i) * C_ + k], x, v[i]);
        }
    }

    for (int i = 0; i < FB_CPT; ++i) {
        const int c = cg * FB_CPT + i;
        const float* __restrict__ img = hidden + ((size_t)b * C_ + c) * HW;
        out[((size_t)b * C_ + c) * HW + px] =
            advect_one(img, u[i], v[i], dt, sp, cp, lon_p,
                       min_lat, min_lon, inv_dlat, inv_dlon);
    }
}

extern "C" void kernel_launch(void* const* d_in, const int* in_sizes, int n_in,
                              void* d_out, int out_size, void* d_ws, size_t ws_size,
                              hipStream_t stream) {
    const float* hidden   = (const float*)d_in[0];
    const float* lat_grid = (const float*)d_in[1];
    const float* lon_grid = (const float*)d_in[2];
    const float* W_vel    = (const float*)d_in[3];
    const float* b_vel    = (const float*)d_in[4];
    const float* dt_p     = (const float*)d_in[5];
    float* out = (float*)d_out;

    const size_t uv_bytes = (size_t)B_ * O_ * HW * sizeof(float); // 66.4 MB
    if (ws_size >= uv_bytes) {
        float* uv = (float*)d_ws;
        nsl_vel<<<B_ * P1_OG * P1_TILES, P1_PXT, 0, stream>>>(hidden, W_vel, b_vel, uv);
        const int n2 = B_ * C_ * HW;
        nsl_advect<<<(n2 + 255) / 256, 256, 0, stream>>>(hidden, lat_grid, lon_grid,
                                                         uv, dt_p, out);
    } else {
        nsl_fused<<<B_ * FB_CG * FB_TILES, FB_PXT, 0, stream>>>(
            hidden, lat_grid, lon_grid, W_vel, b_vel, dt_p, out);
    }
}